// Round 1
// baseline (61.823 us; speedup 1.0000x reference)
//
#include <hip/hip_runtime.h>
#include <math.h>

#define PI_F 3.14159265358979323846f

// ---------------------------------------------------------------------------
// Layout: one batch element per 64-lane wave.
//   amplitude index idx in [0,256): idx = lane*4 + r   (r = 0..3)
//   wire w corresponds to bit (7-w) of idx (wire 0 = MSB, C-order flatten)
//   -> wires 0..5 live in lane bits 5..0 (lane bit j = idx bit j+2, j = 5-w)
//   -> wires 6,7 live in register bits 1,0 of r
// ---------------------------------------------------------------------------

__device__ __forceinline__ void cswap(float& a, float& b, bool c) {
  float t0 = c ? b : a;
  float t1 = c ? a : b;
  a = t0; b = t1;
}

// Generic 1-qubit gate U=[[u00,u01],[u10,u11]] (complex) on wire W.
template<int W>
__device__ __forceinline__ void apply1q(float ar[4], float ai[4],
    float u00r, float u00i, float u01r, float u01i,
    float u10r, float u10i, float u11r, float u11i, int lane)
{
  if constexpr (W <= 5) {
    constexpr int mask = 1 << (5 - W);
    const bool hi = (lane >> (5 - W)) & 1;
    // self coefficient A, partner coefficient B:
    //   bit==0: a' = u00*self + u01*partner
    //   bit==1: a' = u11*self + u10*partner
    const float Ar = hi ? u11r : u00r;
    const float Ai = hi ? u11i : u00i;
    const float Br = hi ? u10r : u01r;
    const float Bi = hi ? u10i : u01i;
#pragma unroll
    for (int r = 0; r < 4; ++r) {
      float pr = __shfl_xor(ar[r], mask, 64);
      float pi = __shfl_xor(ai[r], mask, 64);
      float xr = ar[r], xi = ai[r];
      ar[r] = Ar*xr - Ai*xi + Br*pr - Bi*pi;
      ai[r] = Ar*xi + Ai*xr + Br*pi + Bi*pr;
    }
  } else {
    // register-bit gate: W==6 -> bit1: pairs (0,2),(1,3); W==7 -> bit0: (0,1),(2,3)
#pragma unroll
    for (int p = 0; p < 2; ++p) {
      const int i0 = (W == 6) ? p : 2*p;
      const int i1 = (W == 6) ? p + 2 : 2*p + 1;
      float a0r = ar[i0], a0i = ai[i0];
      float a1r = ar[i1], a1i = ai[i1];
      ar[i0] = u00r*a0r - u00i*a0i + u01r*a1r - u01i*a1i;
      ai[i0] = u00r*a0i + u00i*a0r + u01r*a1i + u01i*a1r;
      ar[i1] = u10r*a0r - u10i*a0i + u11r*a1r - u11i*a1i;
      ai[i1] = u10r*a0i + u10i*a0r + u11r*a1i + u11i*a1r;
    }
  }
}

// CNOT control C, target T: new[idx] = bitC(idx) ? old[idx ^ bitT] : old[idx]
template<int C, int T>
__device__ __forceinline__ void applyCnot(float ar[4], float ai[4], int lane)
{
  if constexpr (C <= 5 && T <= 5) {
    constexpr int mask = 1 << (5 - T);
    const bool ctl = (lane >> (5 - C)) & 1;
#pragma unroll
    for (int r = 0; r < 4; ++r) {
      float pr = __shfl_xor(ar[r], mask, 64);
      float pi = __shfl_xor(ai[r], mask, 64);
      ar[r] = ctl ? pr : ar[r];
      ai[r] = ctl ? pi : ai[r];
    }
  } else if constexpr (C <= 5) {          // target in register bits
    const bool ctl = (lane >> (5 - C)) & 1;
    if constexpr (T == 6) {               // flip bit1: swap (0,2),(1,3)
      cswap(ar[0], ar[2], ctl); cswap(ai[0], ai[2], ctl);
      cswap(ar[1], ar[3], ctl); cswap(ai[1], ai[3], ctl);
    } else {                              // T==7, flip bit0: swap (0,1),(2,3)
      cswap(ar[0], ar[1], ctl); cswap(ai[0], ai[1], ctl);
      cswap(ar[2], ar[3], ctl); cswap(ai[2], ai[3], ctl);
    }
  } else if constexpr (T <= 5) {          // control in register bits
    constexpr int mask = 1 << (5 - T);
    constexpr int r0 = (C == 6) ? 2 : 1;  // regs with control bit set
    constexpr int r1 = 3;
    ar[r0] = __shfl_xor(ar[r0], mask, 64);
    ai[r0] = __shfl_xor(ai[r0], mask, 64);
    ar[r1] = __shfl_xor(ar[r1], mask, 64);
    ai[r1] = __shfl_xor(ai[r1], mask, 64);
  } else {                                // both in register bits
    float t;
    if constexpr (C == 6) {               // ctl bit1 (r=2,3), flip bit0: 2<->3
      t = ar[2]; ar[2] = ar[3]; ar[3] = t;
      t = ai[2]; ai[2] = ai[3]; ai[3] = t;
    } else {                              // C==7: ctl bit0 (r=1,3), flip bit1: 1<->3
      t = ar[1]; ar[1] = ar[3]; ar[3] = t;
      t = ai[1]; ai[1] = ai[3]; ai[3] = t;
    }
  }
}

// ---------------------------------------------------------------------------
// Setup: compute the 16 fixed Rot matrices (2 layers x 8 wires) into d_ws.
// gate t = l*8+w -> 8 floats: u00r,u00i,u01r,u01i,u10r,u10i,u11r,u11i
// ---------------------------------------------------------------------------
__global__ void qbranch_setup(const float* __restrict__ weights,
                              float* __restrict__ gates)
{
  int t = threadIdx.x;
  if (t >= 16) return;
  float phi = weights[t*3 + 0];
  float th  = weights[t*3 + 1];
  float om  = weights[t*3 + 2];
  float ct = cosf(th * 0.5f), st = sinf(th * 0.5f);
  float ap = (phi + om) * 0.5f, am = (phi - om) * 0.5f;
  float cap = cosf(ap), sap = sinf(ap);
  float cam = cosf(am), sam = sinf(am);
  float* g = gates + t*8;
  g[0] =  cap*ct; g[1] = -sap*ct;   // m00 = e^{-i(phi+om)/2} ct
  g[2] = -cam*st; g[3] = -sam*st;   // m01 = -e^{ i(phi-om)/2} st
  g[4] =  cam*st; g[5] = -sam*st;   // m10 =  e^{-i(phi-om)/2} st
  g[6] =  cap*ct; g[7] =  sap*ct;   // m11 =  e^{ i(phi+om)/2} ct
}

// ---------------------------------------------------------------------------
// Main kernel: 4 waves/block, one batch element per wave.
// ---------------------------------------------------------------------------
__global__ __launch_bounds__(256) void qbranch_main(
    const float* __restrict__ x,     // (B,8)
    const float* __restrict__ gates, // 16*8 floats (d_ws)
    const float* __restrict__ Wm,    // (8,64)
    const float* __restrict__ bias,  // (64)
    const float* __restrict__ gamma, // (64)
    const float* __restrict__ beta,  // (64)
    float* __restrict__ out,         // (B,64)
    int B)
{
  const int lane = threadIdx.x & 63;
  const int wid  = threadIdx.x >> 6;
  const int b    = blockIdx.x * 4 + wid;
  if (b >= B) return;

  // per-wire RX half-angle cos/sin on lanes 0..7 (wave-uniform after shfl)
  float cv = 1.0f, sv = 0.0f;
  if (lane < 8) {
    float th2 = tanhf(x[b*8 + lane]) * (PI_F * 0.5f);
    cv = cosf(th2);
    sv = sinf(th2);
  }

  // |0...0>
  float ar[4] = {0.f, 0.f, 0.f, 0.f};
  float ai[4] = {0.f, 0.f, 0.f, 0.f};
  if (lane == 0) ar[0] = 1.0f;

  // --- 8 batch-dependent RX gates: U = [[c,-i s],[-i s,c]] -----------------
#define RX(WW) { float c_ = __shfl(cv, WW, 64); float s_ = __shfl(sv, WW, 64); \
    apply1q<WW>(ar, ai, c_, 0.f, 0.f, -s_, 0.f, -s_, c_, 0.f, lane); }
  RX(0) RX(1) RX(2) RX(3) RX(4) RX(5) RX(6) RX(7)
#undef RX

  // --- fixed Rot gates + CNOT rings ---------------------------------------
#define ROT(LL, WW) { const float* g = gates + ((LL)*8 + (WW))*8; \
    apply1q<WW>(ar, ai, g[0], g[1], g[2], g[3], g[4], g[5], g[6], g[7], lane); }

  // layer 0
  ROT(0,0) ROT(0,1) ROT(0,2) ROT(0,3) ROT(0,4) ROT(0,5) ROT(0,6) ROT(0,7)
  applyCnot<0,1>(ar, ai, lane);
  applyCnot<1,2>(ar, ai, lane);
  applyCnot<2,3>(ar, ai, lane);
  applyCnot<3,4>(ar, ai, lane);
  applyCnot<4,5>(ar, ai, lane);
  applyCnot<5,6>(ar, ai, lane);
  applyCnot<6,7>(ar, ai, lane);
  applyCnot<7,0>(ar, ai, lane);
  // layer 1 (r = 2)
  ROT(1,0) ROT(1,1) ROT(1,2) ROT(1,3) ROT(1,4) ROT(1,5) ROT(1,6) ROT(1,7)
  applyCnot<0,2>(ar, ai, lane);
  applyCnot<1,3>(ar, ai, lane);
  applyCnot<2,4>(ar, ai, lane);
  applyCnot<3,5>(ar, ai, lane);
  applyCnot<4,6>(ar, ai, lane);
  applyCnot<5,7>(ar, ai, lane);
  applyCnot<6,0>(ar, ai, lane);
  applyCnot<7,1>(ar, ai, lane);
#undef ROT

  // --- expectation values <Z_w> -------------------------------------------
  float p0 = ar[0]*ar[0] + ai[0]*ai[0];
  float p1 = ar[1]*ar[1] + ai[1]*ai[1];
  float p2 = ar[2]*ar[2] + ai[2]*ai[2];
  float p3 = ar[3]*ar[3] + ai[3]*ai[3];
  float ps = p0 + p1 + p2 + p3;

  float zp[8];
#pragma unroll
  for (int w = 0; w < 6; ++w)
    zp[w] = ((lane >> (5 - w)) & 1) ? -ps : ps;
  zp[6] = p0 + p1 - p2 - p3;   // bit1 of r
  zp[7] = p0 - p1 + p2 - p3;   // bit0 of r

#pragma unroll
  for (int m = 1; m < 64; m <<= 1) {
#pragma unroll
    for (int w = 0; w < 8; ++w)
      zp[w] += __shfl_xor(zp[w], m, 64);
  }
  // all lanes now hold z_0..z_7

  // --- projection (8 -> 64), lane j computes h[j] --------------------------
  const int j = lane;
  float h = bias[j];
#pragma unroll
  for (int w = 0; w < 8; ++w)
    h = fmaf(zp[w], Wm[w*64 + j], h);

  // --- LayerNorm over 64 lanes ---------------------------------------------
  float mu = h;
#pragma unroll
  for (int m = 1; m < 64; m <<= 1) mu += __shfl_xor(mu, m, 64);
  mu *= (1.0f / 64.0f);
  float d = h - mu;
  float v = d * d;
#pragma unroll
  for (int m = 1; m < 64; m <<= 1) v += __shfl_xor(v, m, 64);
  v *= (1.0f / 64.0f);

  out[b*64 + j] = gamma[j] * d * rsqrtf(v + 1e-5f) + beta[j];
}

// ---------------------------------------------------------------------------
extern "C" void kernel_launch(void* const* d_in, const int* in_sizes, int n_in,
                              void* d_out, int out_size, void* d_ws, size_t ws_size,
                              hipStream_t stream)
{
  const float* x       = (const float*)d_in[0];
  const float* weights = (const float*)d_in[1];
  const float* Wm      = (const float*)d_in[2];
  const float* bias    = (const float*)d_in[3];
  const float* gamma   = (const float*)d_in[4];
  const float* beta    = (const float*)d_in[5];
  float* out   = (float*)d_out;
  float* gates = (float*)d_ws;   // 128 floats used

  const int B = in_sizes[0] / 8;

  hipLaunchKernelGGL(qbranch_setup, dim3(1), dim3(64), 0, stream, weights, gates);
  hipLaunchKernelGGL(qbranch_main, dim3((B + 3) / 4), dim3(256), 0, stream,
                     x, gates, Wm, bias, gamma, beta, out, B);
}

// Round 2
// 35.745 us; speedup vs baseline: 1.7296x; 1.7296x over previous
//
#include <hip/hip_runtime.h>
#include <math.h>

#define PI_F 3.14159265358979323846f

// ---------------------------------------------------------------------------
// Layout: one batch element per 64-lane wave.
//   amplitude physical index p in [0,256): p = lane*4 + r (r = 0..3)
//   wire w <-> idx bit (7-w): wires 0..5 = lane bits 5..0, wires 6,7 = r bits 1,0.
//
// CNOTs are never applied to data. We track stored[p] = psi[A p] with A a GF(2)
// matrix updated per CNOT (A' = F A, F = I + e_t c^T). A 1q gate on logical
// wire w then pairs p with p ^ A^{-1}e_w and selects coefficients by
// hi = row_w(A)·p. All masks below are precomputed by hand for the fixed
// circuit (layer0 CNOT ring r=1, layer1 ring r=2):
//   A1 rows:  {1..7},{0,1},{0,1,2},{0..3},{0..4},{0..5},{0..6},{0..7}
//   A1^-1 cols:{0,1},{1,2},{2,3},{3,4},{4,5},{5,6},{6,7},{0,1,7}
//   A2 rows:  {0,1,2,5,6},{0,1,2,3,6,7},{0,3,4,5,6,7},{2,3},
//             {1,2,5,6,7},{0,1,4,5},{0,3,4,7},{2,3,6,7}
// ---------------------------------------------------------------------------

// Generalized 1q gate. partner(p) = (lane ^ LMASK, r ^ RMASK);
// hi(lane,r) = parity(lane & HIL) ^ parity(r & HIR).
template<int LMASK, int RMASK, int HIL, int HIR>
__device__ __forceinline__ void applyG(float ar[4], float ai[4],
    const float* __restrict__ g, int lane)
{
  const float u00r=g[0], u00i=g[1], u01r=g[2], u01i=g[3],
              u10r=g[4], u10i=g[5], u11r=g[6], u11i=g[7];
  bool pl = false;
  if constexpr (HIL != 0) pl = (__popc(lane & HIL) & 1) != 0;
  float nr[4], ni[4];
#pragma unroll
  for (int r = 0; r < 4; ++r) {
    const float sr = ar[r], si = ai[r];
    float pr, pi;
    if constexpr (LMASK != 0) {
      pr = __shfl_xor(ar[r ^ RMASK], LMASK, 64);
      pi = __shfl_xor(ai[r ^ RMASK], LMASK, 64);
    } else {
      pr = ar[r ^ RMASK]; pi = ai[r ^ RMASK];
    }
    const bool rp = (__popc(r & HIR) & 1) != 0;   // compile-time per r
    const bool hi = pl != rp;
    const float Ar = hi ? u11r : u00r, Ai = hi ? u11i : u00i;
    const float Br = hi ? u10r : u01r, Bi = hi ? u10i : u01i;
    nr[r] = Ar*sr - Ai*si + Br*pr - Bi*pi;
    ni[r] = Ar*si + Ai*sr + Br*pi + Bi*pr;
  }
#pragma unroll
  for (int r = 0; r < 4; ++r) { ar[r] = nr[r]; ai[r] = ni[r]; }
}

// ---------------------------------------------------------------------------
// Setup: 16 fixed Rot matrices (2 layers x 8 wires) -> d_ws (8 floats each).
// ---------------------------------------------------------------------------
__global__ void qbranch_setup(const float* __restrict__ weights,
                              float* __restrict__ gates)
{
  int t = threadIdx.x;
  if (t >= 16) return;
  float phi = weights[t*3 + 0];
  float th  = weights[t*3 + 1];
  float om  = weights[t*3 + 2];
  float ct = cosf(th * 0.5f), st = sinf(th * 0.5f);
  float ap = (phi + om) * 0.5f, am = (phi - om) * 0.5f;
  float cap = cosf(ap), sap = sinf(ap);
  float cam = cosf(am), sam = sinf(am);
  float* g = gates + t*8;
  g[0] =  cap*ct; g[1] = -sap*ct;   // m00
  g[2] = -cam*st; g[3] = -sam*st;   // m01
  g[4] =  cam*st; g[5] = -sam*st;   // m10
  g[6] =  cap*ct; g[7] =  sap*ct;   // m11
}

// ---------------------------------------------------------------------------
__global__ __launch_bounds__(256) void qbranch_main(
    const float* __restrict__ x,     // (B,8)
    const float* __restrict__ gates, // 16*8 floats
    const float* __restrict__ Wm,    // (8,64)
    const float* __restrict__ bias,  // (64)
    const float* __restrict__ gamma, // (64)
    const float* __restrict__ beta,  // (64)
    float* __restrict__ out,         // (B,64)
    int B)
{
  const int lane = threadIdx.x & 63;
  const int wid  = threadIdx.x >> 6;
  const int b    = blockIdx.x * 4 + wid;
  if (b >= B) return;

  // --- trig on lanes 0..15: lane 2w -> cos_w, lane 2w+1 -> sin_w ----------
  float val = 0.f;
  if (lane < 16) {
    float xv = x[b*8 + (lane >> 1)];
    float th = 1.f - 2.f / (__expf(2.f*xv) + 1.f);   // tanh(x)
    float ha = th * (PI_F * 0.5f);                    // theta/2
    float c = __cosf(ha), s = __sinf(ha);
    val = (lane & 1) ? s : c;
  }

  // --- direct product state after 8 RX gates ------------------------------
  // amp(p) = prod_w (bit_w ? sin_w : cos_w) * (-i)^popc(p)
  float m0 = __shfl(val,  0 + ((lane >> 5) & 1), 64);
  float m1 = __shfl(val,  2 + ((lane >> 4) & 1), 64);
  float m2 = __shfl(val,  4 + ((lane >> 3) & 1), 64);
  float m3 = __shfl(val,  6 + ((lane >> 2) & 1), 64);
  float m4 = __shfl(val,  8 + ((lane >> 1) & 1), 64);
  float m5 = __shfl(val, 10 + ( lane       & 1), 64);
  float p6 = m0*m1*m2*m3*m4*m5;
  float c6 = __shfl(val, 12, 64), s6 = __shfl(val, 13, 64);
  float c7 = __shfl(val, 14, 64), s7 = __shfl(val, 15, 64);

  float ar[4], ai[4];
  {
    const float mag[4] = { p6*c6*c7, p6*c6*s7, p6*s6*c7, p6*s6*s7 };
    const int kl = __popc(lane);
#pragma unroll
    for (int r = 0; r < 4; ++r) {
      const int k = kl + ((r >> 1) & 1) + (r & 1);   // popc(p)
      float sgn = (k & 2) ? -mag[r] : mag[r];
      ar[r] = (k & 1) ? 0.f : sgn;
      ai[r] = (k & 1) ? -sgn : 0.f;
    }
  }

  // --- layer 0 Rot gates (A = I) ------------------------------------------
  applyG<0x20, 0, 0x20, 0>(ar, ai, gates + 0*8, lane);
  applyG<0x10, 0, 0x10, 0>(ar, ai, gates + 1*8, lane);
  applyG<0x08, 0, 0x08, 0>(ar, ai, gates + 2*8, lane);
  applyG<0x04, 0, 0x04, 0>(ar, ai, gates + 3*8, lane);
  applyG<0x02, 0, 0x02, 0>(ar, ai, gates + 4*8, lane);
  applyG<0x01, 0, 0x01, 0>(ar, ai, gates + 5*8, lane);
  applyG<0x00, 2, 0x00, 2>(ar, ai, gates + 6*8, lane);
  applyG<0x00, 1, 0x00, 1>(ar, ai, gates + 7*8, lane);

  // --- layer 1 Rot gates (A = A1, CNOT ring r=1 absorbed) -----------------
  applyG<0x30, 0, 0x1F, 3>(ar, ai, gates +  8*8, lane);
  applyG<0x18, 0, 0x30, 0>(ar, ai, gates +  9*8, lane);
  applyG<0x0C, 0, 0x38, 0>(ar, ai, gates + 10*8, lane);
  applyG<0x06, 0, 0x3C, 0>(ar, ai, gates + 11*8, lane);
  applyG<0x03, 0, 0x3E, 0>(ar, ai, gates + 12*8, lane);
  applyG<0x01, 2, 0x3F, 0>(ar, ai, gates + 13*8, lane);
  applyG<0x00, 3, 0x3F, 2>(ar, ai, gates + 14*8, lane);
  applyG<0x30, 1, 0x3F, 3>(ar, ai, gates + 15*8, lane);

  // --- Z expectations with A2 sign masks ----------------------------------
  const float pp0 = ar[0]*ar[0] + ai[0]*ai[0];
  const float pp1 = ar[1]*ar[1] + ai[1]*ai[1];
  const float pp2 = ar[2]*ar[2] + ai[2]*ai[2];
  const float pp3 = ar[3]*ar[3] + ai[3]*ai[3];
  const float q0 = pp0 + pp1 + pp2 + pp3;
  const float q1 = pp0 - pp1 + pp2 - pp3;
  const float q2 = pp0 + pp1 - pp2 - pp3;
  const float q3 = pp0 - pp1 - pp2 + pp3;

  float zp[8];
  zp[0] = (__popc(lane & 0x39) & 1) ? -q2 : q2;
  zp[1] = (__popc(lane & 0x3C) & 1) ? -q3 : q3;
  zp[2] = (__popc(lane & 0x27) & 1) ? -q3 : q3;
  zp[3] = (__popc(lane & 0x0C) & 1) ? -q0 : q0;
  zp[4] = (__popc(lane & 0x19) & 1) ? -q3 : q3;
  zp[5] = (__popc(lane & 0x33) & 1) ? -q0 : q0;
  zp[6] = (__popc(lane & 0x26) & 1) ? -q1 : q1;
  zp[7] = (__popc(lane & 0x0C) & 1) ? -q3 : q3;

  // --- split-butterfly reduce: lane ends with z_{4*b0+2*b1+b2} ------------
  const bool lb0 = (lane & 1) != 0, lb1 = (lane & 2) != 0, lb2 = (lane & 4) != 0;
  float u[4];
#pragma unroll
  for (int k = 0; k < 4; ++k) {
    float snd = lb0 ? zp[k] : zp[k+4];
    float rcv = __shfl_xor(snd, 1, 64);
    u[k] = (lb0 ? zp[k+4] : zp[k]) + rcv;
  }
  float v2[2];
#pragma unroll
  for (int k = 0; k < 2; ++k) {
    float snd = lb1 ? u[k] : u[k+2];
    float rcv = __shfl_xor(snd, 2, 64);
    v2[k] = (lb1 ? u[k+2] : u[k]) + rcv;
  }
  float snd3 = lb2 ? v2[0] : v2[1];
  float rcv3 = __shfl_xor(snd3, 4, 64);
  float zs = (lb2 ? v2[1] : v2[0]) + rcv3;
  zs += __shfl_xor(zs, 8, 64);
  zs += __shfl_xor(zs, 16, 64);
  zs += __shfl_xor(zs, 32, 64);

  const float z0 = __shfl(zs, 0, 64);
  const float z1 = __shfl(zs, 4, 64);
  const float z2 = __shfl(zs, 2, 64);
  const float z3 = __shfl(zs, 6, 64);
  const float z4 = __shfl(zs, 1, 64);
  const float z5 = __shfl(zs, 5, 64);
  const float z6 = __shfl(zs, 3, 64);
  const float z7 = __shfl(zs, 7, 64);

  // --- projection (8 -> 64), lane j computes h[j] --------------------------
  const int j = lane;
  float h = bias[j];
  h = fmaf(z0, Wm[0*64 + j], h);
  h = fmaf(z1, Wm[1*64 + j], h);
  h = fmaf(z2, Wm[2*64 + j], h);
  h = fmaf(z3, Wm[3*64 + j], h);
  h = fmaf(z4, Wm[4*64 + j], h);
  h = fmaf(z5, Wm[5*64 + j], h);
  h = fmaf(z6, Wm[6*64 + j], h);
  h = fmaf(z7, Wm[7*64 + j], h);

  // --- LayerNorm: fused sum/sumsq reduce ----------------------------------
  float S = h, Q = h*h;
  float snd4 = lb0 ? S : Q;
  float rcv4 = __shfl_xor(snd4, 1, 64);
  float acc = (lb0 ? Q : S) + rcv4;
  acc += __shfl_xor(acc, 2, 64);
  acc += __shfl_xor(acc, 4, 64);
  acc += __shfl_xor(acc, 8, 64);
  acc += __shfl_xor(acc, 16, 64);
  acc += __shfl_xor(acc, 32, 64);
  const float Ssum = __shfl(acc, 0, 64);
  const float Qsum = __shfl(acc, 1, 64);
  const float mu  = Ssum * (1.f/64.f);
  const float var = Qsum * (1.f/64.f) - mu*mu;

  out[b*64 + j] = gamma[j] * (h - mu) * rsqrtf(var + 1e-5f) + beta[j];
}

// ---------------------------------------------------------------------------
extern "C" void kernel_launch(void* const* d_in, const int* in_sizes, int n_in,
                              void* d_out, int out_size, void* d_ws, size_t ws_size,
                              hipStream_t stream)
{
  const float* x       = (const float*)d_in[0];
  const float* weights = (const float*)d_in[1];
  const float* Wm      = (const float*)d_in[2];
  const float* bias    = (const float*)d_in[3];
  const float* gamma   = (const float*)d_in[4];
  const float* beta    = (const float*)d_in[5];
  float* out   = (float*)d_out;
  float* gates = (float*)d_ws;   // 128 floats used

  const int B = in_sizes[0] / 8;

  hipLaunchKernelGGL(qbranch_setup, dim3(1), dim3(64), 0, stream, weights, gates);
  hipLaunchKernelGGL(qbranch_main, dim3((B + 3) / 4), dim3(256), 0, stream,
                     x, gates, Wm, bias, gamma, beta, out, B);
}